// Round 2
// baseline (531.788 us; speedup 1.0000x reference)
//
#include <hip/hip_runtime.h>

#define TAGS 64
#define MAXT 512
#define NEG  -10000.0f
#define CH   8    // steps per chunk (producer publishes, consumers trail 1 chunk)
#define NCONS 2   // consumer waves

// Round-8: producer/consumer wave split.
// Falsified theory: round-7 removed LDS from the recurrence (64x readlane
// broadcast) and still landed at ~1409 cyc/step == the 1330-1410 plateau of
// every LDS variant. VALUBusy 37% x 1409 ~= 520 cyc = exactly the issue cost
// of the ~330-instr step body -> the other 60% is in-wave dependency stall.
// The invariant across ALL plateau variants is the argmax equality-scan:
// 64x (v_cmp -> VCC/SGPR -> v_cndmask) pairs, each exposing a ~4-7 cyc
// VALU->SGPR->VALU hazard with only 1 wave/SIMD to hide it (~580 cyc/step).
// The argmax does NOT feed the recurrence: only nf (the max value) is serial.
// So: wave 0 (producer) runs ONLY the value recurrence (no cmp/cndmask at
// all, ~165 instr/step) and publishes fv per step to a double-buffered LDS
// ring; waves 1-2 (consumers) trail one chunk behind, recompute c[] from the
// published fv (16 broadcast ds_read_b128 - latency-tolerant, off-chain),
// recompute m (fmax is exact -> bit-identical), and do the equality-scan +
// bptr write in parallel. One __syncthreads per 8-step chunk.
// fvbuf protocol: fvbuf[c&1][i] = fv(c*CH + i - 1). Producer seeds slot 0
// with the pre-chunk nf, then step i writes slot i+1 (i+1<CH); the last
// step's value becomes next chunk's slot 0. Double buffer => consumer reads
// of chunk c-1 never collide with producer writes of chunk c.
__global__ __launch_bounds__(192, 3) void crf_viterbi(
    const float* __restrict__ feats,   // [B, T, K]
    const float* __restrict__ weights, // [K, K] (weights[next][prev])
    const int*   __restrict__ lens,    // [B]
    float*       __restrict__ out,     // [B] scores ++ [B*T] paths (as f32)
    int B, int T)
{
    const int b    = blockIdx.x;
    const int tid  = threadIdx.x;
    const int wv   = tid >> 6;                 // 0 = producer, 1..2 = consumers
    const int lane = tid & 63;                 // next tag
    const int len  = lens[b];                  // 1..T

    __shared__ unsigned char  bptr[MAXT * TAGS];   // 32 KB
    __shared__ unsigned short path[MAXT];          // 1 KB
    __shared__ float fvbuf[2][CH][TAGS];           // 4 KB fv ring
    // ~37.9 KB LDS -> 4 blocks/CU; 12 waves/CU; VGPR cap 170 via (192,3).

#define F3(a, b, c) fmaxf(fmaxf((a), (b)), (c))
#define M3(a, b, c) min(min((a), (b)), (c))

    // W row for this lane (all waves need it)
    float wf[TAGS];
    #pragma unroll
    for (int i = 0; i < 16; ++i) {
        const float4 q = *reinterpret_cast<const float4*>(weights + lane * TAGS + i * 4);
        wf[4*i+0] = q.x; wf[4*i+1] = q.y; wf[4*i+2] = q.z; wf[4*i+3] = q.w;
    }
    const float wEnd = weights[1 * TAGS + lane];  // transition into END

    const float* fb  = feats + (size_t)b * T * TAGS;
    const int    cap = len * TAGS;
    const int    nch = (len + CH - 1) / CH;

    float nf = (lane == 0) ? 0.0f : NEG;          // fv^(0); START = 0

    // value-only 3-ary max tree (identical structure to verified kernel)
    auto maxtree = [&](const float* c) -> float {
        float v1[22];
        #pragma unroll
        for (int k = 0; k < 21; ++k) v1[k] = F3(c[3*k], c[3*k+1], c[3*k+2]);
        v1[21] = c[63];
        float v2[8];
        #pragma unroll
        for (int k = 0; k < 7; ++k) v2[k] = F3(v1[3*k], v1[3*k+1], v1[3*k+2]);
        v2[7] = v1[21];
        const float v30 = F3(v2[0], v2[1], v2[2]);
        const float v31 = F3(v2[3], v2[4], v2[5]);
        const float v32 = fmaxf(v2[6], v2[7]);
        return F3(v30, v31, v32);
    };
    // first p with c[p]==m (numpy first-occurrence; exact f32 ==; no NaNs)
    auto argscan = [&](const float* c, float m) -> unsigned {
        unsigned e[64];
        #pragma unroll
        for (int p = 0; p < 64; ++p) e[p] = (c[p] == m) ? (unsigned)p : 64u;
        unsigned u1[22];
        #pragma unroll
        for (int k = 0; k < 21; ++k) u1[k] = M3(e[3*k], e[3*k+1], e[3*k+2]);
        u1[21] = e[63];
        unsigned u2[8];
        #pragma unroll
        for (int k = 0; k < 7; ++k) u2[k] = M3(u1[3*k], u1[3*k+1], u1[3*k+2]);
        u2[7] = u1[21];
        const unsigned u30 = M3(u2[0], u2[1], u2[2]);
        const unsigned u31 = M3(u2[3], u2[4], u2[5]);
        const unsigned u32 = min(u2[6], u2[7]);
        return M3(u30, u31, u32);
    };

    // producer feat prefetch: chunk c in fcur, chunk c+1 in fnx
    float fcur[CH], fnx[CH];
    if (wv == 0) {
        #pragma unroll
        for (int i = 0; i < CH; ++i) {
            int o = i * TAGS + lane; if (o >= cap) o = lane;
            fcur[i] = fb[o];
        }
        #pragma unroll
        for (int i = 0; i < CH; ++i) {
            int o = (CH + i) * TAGS + lane; if (o >= cap) o = lane;
            fnx[i] = fb[o];
        }
    }

    for (int c = 0; c <= nch; ++c) {
        if (wv == 0 && c < nch) {
            // ---- producer: value recurrence for chunk c ----
            const int n = min(CH, len - c * CH);
            fvbuf[c & 1][0][lane] = nf;                  // fv(c*CH - 1)
            #pragma unroll
            for (int i = 0; i < CH; ++i) {
                if (i < n) {
                    float cv[64];
                    #pragma unroll
                    for (int p = 0; p < 64; ++p) {
                        const float fvp = __uint_as_float(
                            __builtin_amdgcn_readlane(__float_as_uint(nf), p));
                        cv[p] = fvp + wf[p];
                    }
                    nf = maxtree(cv) + fcur[i];          // emission after max
                    if (i + 1 < CH) fvbuf[c & 1][i + 1][lane] = nf;
                }
            }
            // rotate prefetch: fcur <- fnx, load chunk c+2
            #pragma unroll
            for (int i = 0; i < CH; ++i) fcur[i] = fnx[i];
            #pragma unroll
            for (int i = 0; i < CH; ++i) {
                int o = (c + 2) * CH * TAGS + i * TAGS + lane; if (o >= cap) o = lane;
                fnx[i] = fb[o];
            }
        }
        if (wv > 0 && c > 0) {
            // ---- consumers: argmax + bptr for chunk c-1 ----
            const int cc = c - 1;
            const int n  = min(CH, len - cc * CH);
            for (int i = wv - 1; i < n; i += NCONS) {
                float cv[64];
                #pragma unroll
                for (int g = 0; g < 16; ++g) {
                    const float4 q = *reinterpret_cast<const float4*>(&fvbuf[cc & 1][i][4 * g]);
                    cv[4*g+0] = q.x + wf[4*g+0];
                    cv[4*g+1] = q.y + wf[4*g+1];
                    cv[4*g+2] = q.z + wf[4*g+2];
                    cv[4*g+3] = q.w + wf[4*g+3];
                }
                const float    m   = maxtree(cv);        // exact: fmax order-free
                const unsigned idx = argscan(cv, m);
                bptr[(cc * CH + i) * TAGS + lane] = (unsigned char)idx;
            }
        }
        __syncthreads();
    }

    if (wv != 0) return;   // consumers done; no more block barriers below

    // terminal = fv + W[END][prev]; first-max argmax via shuffle butterfly
    float tv = nf + wEnd;
    int   ti = lane;
    #pragma unroll
    for (int off = 32; off >= 1; off >>= 1) {
        const float ov = __shfl_xor(tv, off);
        const int   oi = __shfl_xor(ti, off);
        if (ov > tv || (ov == tv && oi < ti)) { tv = ov; ti = oi; }
    }
    if (lane == 0) out[b] = tv;
    const int bestlast = ti;                      // uniform across lanes

    // padding region: path[t] = bestlast for t in [len-1, T)
    for (int t = lane; t < T; t += 64)
        if (t >= len - 1) path[t] = (unsigned short)bestlast;
    __builtin_amdgcn_wave_barrier();

    // serial chase (lane 0, LDS-resident backpointers)
    if (lane == 0) {
        int tag = bestlast;
        for (int t = len - 1; t >= 1; --t) {
            tag = bptr[t * TAGS + tag];
            path[t - 1] = (unsigned short)tag;
        }
    }
    __builtin_amdgcn_wave_barrier();

    // coalesced path writeback (tags as float32)
    float* pout = out + B + (size_t)b * T;
    for (int t = lane; t < T; t += 64)
        pout[t] = (float)path[t];
}

extern "C" void kernel_launch(void* const* d_in, const int* in_sizes, int n_in,
                              void* d_out, int out_size, void* d_ws, size_t ws_size,
                              hipStream_t stream) {
    const float* feats   = (const float*)d_in[0];
    const float* weights = (const float*)d_in[1];
    const int*   lens    = (const int*)d_in[2];
    float*       out     = (float*)d_out;

    const int B = in_sizes[2];
    const int T = in_sizes[0] / (B * TAGS);

    crf_viterbi<<<dim3(B), dim3(192), 0, stream>>>(feats, weights, lens, out, B, T);
}

// Round 3
// 450.879 us; speedup vs baseline: 1.1794x; 1.1794x over previous
//
#include <hip/hip_runtime.h>

#define TAGS 64
#define MAXT 512
#define NEG  -10000.0f
#define CH   8   // feat-staging chunk: steps per LDS buffer

// One wave (64 lanes) per batch. lane = "next" tag.
// Round-9: round-0 body (best verified, 283us/dispatch) with ONE change:
// the argmax equality-scan no longer uses v_cmp/v_cndmask.
// Theory: at 1 wave/SIMD the 64x (v_cmp -> VCC/SGPR -> v_cndmask) pairs
// serialize on the condition register (~450-550 cyc/step of exposed
// VALU->SGPR->VALU hazard) and are the invariant behind the 1330-1410
// cyc/step plateau of rounds 0/1 (round 2's producer/consumer test was
// voided by VGPR spills: VGPR_Count=84 < the 128 live array regs).
// Fix: branch-free float-bit argmax. d = m - c[p] >= 0 and d == +0 iff
// c[p]==m (IEEE: a-b with a>=b rounds to +0 only on equality). Bits of a
// non-negative f32 are monotonic, so key[p] = (bits(d) & ~63) | p equals p
// iff c[p]==m, else >= 64 (nonzero d implies bits(d) >= 64 unless d <
// 2^-143 -- requires two scores equal to ~1e-43, impossible here). min3_u32
// tree over key[] = first-occurrence argmax, ties correct, zero SGPR/VCC
// writes, fully pipelined. Same instruction count, no hazards.
// (Dead lds_pad from round 0 removed -- rocprof showed it was DCE'd.)
__global__ __launch_bounds__(64, 1) void crf_viterbi(
    const float* __restrict__ feats,   // [B, T, K]
    const float* __restrict__ weights, // [K, K] (weights[next][prev])
    const int*   __restrict__ lens,    // [B]
    float*       __restrict__ out,     // [B] scores ++ [B*T] paths (as f32)
    int B, int T)
{
    const int b    = blockIdx.x;
    const int lane = threadIdx.x;              // next tag
    const int len  = lens[b];                  // 1..T

    __shared__ float fv[TAGS];
    __shared__ float fbuf[2][CH * TAGS];       // 2 x 2 KB feat staging
    __shared__ unsigned char  bptr[MAXT * TAGS];
    __shared__ unsigned short path[MAXT];
    // ~33.8 KB LDS -> 4 blocks/CU.

    // W row for this lane (as float4 quads)
    float4 w4[16];
    #pragma unroll
    for (int i = 0; i < 16; ++i)
        w4[i] = *reinterpret_cast<const float4*>(weights + lane * TAGS + i * 4);
    const float wEnd = weights[1 * TAGS + lane];  // transition into END

    fv[lane] = (lane == 0) ? 0.0f : NEG;          // START = 0

    const float* fb  = feats + (size_t)b * T * TAGS;
    const int    lim = len * TAGS - 4;            // clamp for tail loads

    float nf = NEG;                               // this lane's running fv

#define F3(a, b, c) fmaxf(fmaxf((a), (b)), (c))
#define M3(a, b, c) min(min((a), (b)), (c))

    auto step = [&](int cbuf, int i, int t) {
        const float feat = fbuf[cbuf][i * TAGS + lane];  // early, off-chain
        // gather fv quads (16x ds_read_b128)
        float4 fq[16];
        #pragma unroll
        for (int g = 0; g < 16; ++g)
            fq[g] = *reinterpret_cast<const float4*>(&fv[g * 4]);
        // c = fv + w
        float4 c4[16];
        #pragma unroll
        for (int g = 0; g < 16; ++g) {
            c4[g].x = fq[g].x + w4[g].x;
            c4[g].y = fq[g].y + w4[g].y;
            c4[g].z = fq[g].z + w4[g].z;
            c4[g].w = fq[g].w + w4[g].w;
        }
        const float* c = reinterpret_cast<const float*>(c4);

        // value-only max: 3-ary tree (v_max3_f32), depth 4
        float v1[22];
        #pragma unroll
        for (int k = 0; k < 21; ++k) v1[k] = F3(c[3*k], c[3*k+1], c[3*k+2]);
        v1[21] = c[63];
        float v2[8];
        #pragma unroll
        for (int k = 0; k < 7; ++k) v2[k] = F3(v1[3*k], v1[3*k+1], v1[3*k+2]);
        v2[7] = v1[21];
        const float v30 = F3(v2[0], v2[1], v2[2]);
        const float v31 = F3(v2[3], v2[4], v2[5]);
        const float v32 = fmaxf(v2[6], v2[7]);
        const float m   = F3(v30, v31, v32);

        nf = m + feat;                 // emission added after max
        fv[lane] = nf;                 // unblocks step t+1

        // branch-free first-occurrence argmax, no SGPR/VCC traffic:
        // d = m - c[p] >= 0, +0 iff c[p]==m (exact f32; no NaNs in data).
        // key = (bits(d) & ~63) | p  ->  p iff max, else >= 64.
        unsigned e[64];
        #pragma unroll
        for (int p = 0; p < 64; ++p) {
            const float d = m - c[p];
            e[p] = (__float_as_uint(d) & 0xFFFFFFC0u) | (unsigned)p;
        }
        unsigned u1[22];
        #pragma unroll
        for (int k = 0; k < 21; ++k) u1[k] = M3(e[3*k], e[3*k+1], e[3*k+2]);
        u1[21] = e[63];
        unsigned u2[8];
        #pragma unroll
        for (int k = 0; k < 7; ++k) u2[k] = M3(u1[3*k], u1[3*k+1], u1[3*k+2]);
        u2[7] = u1[21];
        const unsigned u30 = M3(u2[0], u2[1], u2[2]);
        const unsigned u31 = M3(u2[3], u2[4], u2[5]);
        const unsigned u32 = min(u2[6], u2[7]);
        const unsigned idx = M3(u30, u31, u32);   // == winner lane index

        bptr[t * TAGS + lane] = (unsigned char)idx;
    };

    // prologue: stage chunk 0 -> fbuf[0]; issue chunk-1 loads
    {
        int o0 = 4 * lane;        if (o0 > lim) o0 = lim;
        int o1 = 256 + 4 * lane;  if (o1 > lim) o1 = lim;
        *reinterpret_cast<float4*>(&fbuf[0][4 * lane])       = *reinterpret_cast<const float4*>(fb + o0);
        *reinterpret_cast<float4*>(&fbuf[0][256 + 4 * lane]) = *reinterpret_cast<const float4*>(fb + o1);
    }
    float4 n0, n1;
    {
        int o0 = CH * TAGS + 4 * lane;        if (o0 > lim) o0 = lim;
        int o1 = CH * TAGS + 256 + 4 * lane;  if (o1 > lim) o1 = lim;
        n0 = *reinterpret_cast<const float4*>(fb + o0);
        n1 = *reinterpret_cast<const float4*>(fb + o1);
    }

    int cb = 0;
    const int nfull = len / CH;
    for (int c = 0; c < nfull; ++c) {
        #pragma unroll
        for (int i = 0; i < CH; ++i) step(cb, i, c * CH + i);
        // stage chunk c+1 (loads landed ~8 steps ago), issue chunk c+2
        *reinterpret_cast<float4*>(&fbuf[cb ^ 1][4 * lane])       = n0;
        *reinterpret_cast<float4*>(&fbuf[cb ^ 1][256 + 4 * lane]) = n1;
        {
            int o0 = (c + 2) * CH * TAGS + 4 * lane;        if (o0 > lim) o0 = lim;
            int o1 = (c + 2) * CH * TAGS + 256 + 4 * lane;  if (o1 > lim) o1 = lim;
            n0 = *reinterpret_cast<const float4*>(fb + o0);
            n1 = *reinterpret_cast<const float4*>(fb + o1);
        }
        cb ^= 1;
    }
    const int rem = len - nfull * CH;             // 0..7 remainder steps
    for (int i = 0; i < rem; ++i) step(cb, i, nfull * CH + i);

    // terminal = fv + W[END][prev]; first-max argmax via shuffle butterfly
    float tv = nf + wEnd;
    int   ti = lane;
    #pragma unroll
    for (int off = 32; off >= 1; off >>= 1) {
        const float ov = __shfl_xor(tv, off);
        const int   oi = __shfl_xor(ti, off);
        if (ov > tv || (ov == tv && oi < ti)) { tv = ov; ti = oi; }
    }
    if (lane == 0) out[b] = tv;
    const int bestlast = ti;                      // uniform across lanes

    // padding region: path[t] = bestlast for t in [len-1, T)
    for (int t = lane; t < T; t += 64)
        if (t >= len - 1) path[t] = (unsigned short)bestlast;
    __builtin_amdgcn_wave_barrier();

    // serial chase (lane 0, LDS-resident backpointers)
    if (lane == 0) {
        int tag = bestlast;
        for (int t = len - 1; t >= 1; --t) {
            tag = bptr[t * TAGS + tag];
            path[t - 1] = (unsigned short)tag;
        }
    }
    __builtin_amdgcn_wave_barrier();

    // coalesced path writeback (tags as float32)
    float* pout = out + B + (size_t)b * T;
    for (int t = lane; t < T; t += 64)
        pout[t] = (float)path[t];
}

extern "C" void kernel_launch(void* const* d_in, const int* in_sizes, int n_in,
                              void* d_out, int out_size, void* d_ws, size_t ws_size,
                              hipStream_t stream) {
    const float* feats   = (const float*)d_in[0];
    const float* weights = (const float*)d_in[1];
    const int*   lens    = (const int*)d_in[2];
    float*       out     = (float*)d_out;

    const int B = in_sizes[2];
    const int T = in_sizes[0] / (B * TAGS);

    crf_viterbi<<<dim3(B), dim3(64), 0, stream>>>(feats, weights, lens, out, B, T);
}